// Round 1
// baseline (396.971 us; speedup 1.0000x reference)
//
#include <hip/hip_runtime.h>
#include <hip/hip_bf16.h>

#define KP    32
#define NIN_  64
#define RNK   16
#define NOUT_ 128
#define HID_  64
#define CDIM  1024   // RNK*NIN_
#define EPS_  1e-7f
#define LNEPS 1e-5f
#define NTOT  16384  // B*N

__device__ __forceinline__ float rsum8(float v) {
  v += __shfl_xor(v, 1); v += __shfl_xor(v, 2); v += __shfl_xor(v, 4);
  return v;
}
__device__ __forceinline__ float rsum16(float v) {
  v += __shfl_xor(v, 1); v += __shfl_xor(v, 2);
  v += __shfl_xor(v, 4); v += __shfl_xor(v, 8);
  return v;
}

// One block per (b,n): rifeat -> LN(ri@w1)+relu -> @w2 -> kern^T @ feat -> A row (1024)
__global__ __launch_bounds__(256) void k1_contract(
    const float* __restrict__ fp,   // (NTOT, KP, 3)
    const float* __restrict__ feat, // (NTOT, KP, NIN_)
    const float* __restrict__ ep,   // (NTOT, 3)
    const float* __restrict__ w1,   // (8, HID_)
    const float* __restrict__ b1,   // (HID_)
    const float* __restrict__ g1,   // (HID_)
    const float* __restrict__ be1,  // (HID_)
    const float* __restrict__ w2,   // (HID_, RNK)
    const float* __restrict__ b2,   // (RNK)
    float* __restrict__ A)          // (NTOT, CDIM)
{
  __shared__ __align__(16) float w1S[8 * HID_];
  __shared__ __align__(16) float w2S[HID_ * RNK];
  __shared__ __align__(16) float featS[KP * NIN_];
  __shared__ float riS[KP][9];
  __shared__ float hdnS[KP][HID_ + 1];
  __shared__ float kernT[RNK][KP + 1];

  const int t = threadIdx.x;
  const long bn = blockIdx.x;

  // stage weights + feat tile
  if (t < 128)
    reinterpret_cast<float4*>(w1S)[t] = reinterpret_cast<const float4*>(w1)[t];
  reinterpret_cast<float4*>(w2S)[t] = reinterpret_cast<const float4*>(w2)[t];
  {
    const float4* fg = reinterpret_cast<const float4*>(feat + bn * (KP * NIN_));
    float4* fs = reinterpret_cast<float4*>(featS);
    fs[t] = fg[t];
    fs[t + 256] = fg[t + 256];
  }

  // phase 1: rifeat (lanes 0..31, one per k)
  if (t < KP) {
    const float* prp = fp + (bn * KP + t) * 3;
    float prx = prp[0], pry = prp[1], prz = prp[2];
    const float* psp = ep + bn * 3;
    float psx = psp[0], psy = psp[1], psz = psp[2];

    float sx = prx, sy = pry, sz = prz;
    #pragma unroll
    for (int m = 16; m >= 1; m >>= 1) {
      sx += __shfl_xor(sx, m); sy += __shfl_xor(sy, m); sz += __shfl_xor(sz, m);
    }
    const float inv = 1.f / 32.f;
    float mx = sx * inv, my = sy * inv, mz = sz * inv;

    float l1x = mx - prx, l1y = my - pry, l1z = mz - prz;
    float l2x = prx - psx, l2y = pry - psy, l2z = prz - psz;
    float l3x = psx - mx, l3y = psy - my, l3z = psz - mz;
    float l1n = sqrtf(l1x * l1x + l1y * l1y + l1z * l1z);
    float l2n = sqrtf(l2x * l2x + l2y * l2y + l2z * l2z);
    float l3n = sqrtf(l3x * l3x + l3y * l3y + l3z * l3z);
    float th1 = (l1x * l2x + l1y * l2y + l1z * l2z) / (l1n * l2n + EPS_);
    float th2 = (l2x * l3x + l2y * l3y + l2z * l3z) / (l2n * l3n + EPS_);
    float th3 = (l3x * l1x + l3y * l1y + l3z * l1z) / (l3n * l1n + EPS_);
    float h   = sqrtf(prx * prx + pry * pry + prz * prz);
    float psn = sqrtf(psx * psx + psy * psy + psz * psz);
    // row 2 of Zm(-ps.z)@Ym(-pol)@Zm(-az) == ps/|ps|  =>  res2 = p̂s · p̂r
    float c = (psx * prx + psy * pry + psz * prz) / (psn * h);
    c = fminf(1.f, fmaxf(-1.f, c));
    float txj = acosf(c) * 0.31830988618379067f; // 1/pi

    riS[t][0] = txj; riS[t][1] = h;   riS[t][2] = l1n; riS[t][3] = l2n;
    riS[t][4] = l3n; riS[t][5] = th1; riS[t][6] = th2; riS[t][7] = th3;
  }
  __syncthreads();

  // phase 2: hdn = relu(LN(ri@w1 + b1)); 8 threads per k, 8 h-values each (h = s + 8j)
  {
    const int k = t >> 3, s = t & 7;
    float rv[8];
    #pragma unroll
    for (int x = 0; x < 8; ++x) rv[x] = riS[k][x];
    float vals[8];
    #pragma unroll
    for (int j = 0; j < 8; ++j) {
      const int hh = s + 8 * j;
      float a = b1[hh];
      #pragma unroll
      for (int x = 0; x < 8; ++x) a += rv[x] * w1S[x * HID_ + hh];
      vals[j] = a;
    }
    float psum = 0.f;
    #pragma unroll
    for (int j = 0; j < 8; ++j) psum += vals[j];
    const float mu = rsum8(psum) * (1.f / 64.f);
    float vsum = 0.f;
    #pragma unroll
    for (int j = 0; j < 8; ++j) { float d = vals[j] - mu; vsum += d * d; }
    const float rstd = rsqrtf(rsum8(vsum) * (1.f / 64.f) + LNEPS);
    #pragma unroll
    for (int j = 0; j < 8; ++j) {
      const int hh = s + 8 * j;
      float v = (vals[j] - mu) * rstd * g1[hh] + be1[hh];
      hdnS[k][hh] = fmaxf(v, 0.f);
    }
  }
  __syncthreads();

  // phase 3: kern[k][r] = b2[r] + hdn[k]·w2[:,r]  (512 outputs)
  #pragma unroll
  for (int it = 0; it < 2; ++it) {
    const int idx = t + 256 * it;
    const int k = idx >> 4, r = idx & 15;
    float a = b2[r];
    for (int hh = 0; hh < HID_; ++hh) a += hdnS[k][hh] * w2S[hh * RNK + r];
    kernT[r][k] = a;
  }
  __syncthreads();

  // phase 4: cont[r][i] = sum_k kernT[r][k]*featS[k][i]; thread t owns j=4t..4t+3
  {
    const int r = t >> 4;
    const int i0 = (t & 15) * 4;
    float4 acc = {0.f, 0.f, 0.f, 0.f};
    #pragma unroll 8
    for (int k = 0; k < KP; ++k) {
      const float kv = kernT[r][k];
      const float4 fv = *reinterpret_cast<const float4*>(&featS[k * NIN_ + i0]);
      acc.x += kv * fv.x; acc.y += kv * fv.y; acc.z += kv * fv.z; acc.w += kv * fv.w;
    }
    reinterpret_cast<float4*>(A + bn * CDIM)[t] = acc;
  }
}

// GEMM (NTOT x CDIM) @ (CDIM x NOUT_) + bwo, then LN over NOUT_, fused.
// BM=64 rows/block, full 128 cols; 512 threads; 2x8 micro-tile.
__global__ __launch_bounds__(512) void k2_gemm_ln(
    const float* __restrict__ A,   // (NTOT, CDIM)
    const float* __restrict__ wo,  // (CDIM, NOUT_)
    const float* __restrict__ bwo, // (NOUT_)
    const float* __restrict__ gln, // (NOUT_)
    const float* __restrict__ bln, // (NOUT_)
    float* __restrict__ out)       // (NTOT, NOUT_)
{
  __shared__ __align__(16) float AsT[32][68];  // [kk][row], padded, 16B-aligned cols
  __shared__ __align__(16) float Bs[32][NOUT_];

  const int t = threadIdx.x;
  const int row0 = blockIdx.x * 64;
  const int tr = t >> 4;   // 0..31 -> rows 2tr, 2tr+1
  const int tc = t & 15;   // cols 8tc..8tc+7

  float acc[2][8];
  #pragma unroll
  for (int r = 0; r < 2; ++r)
    #pragma unroll
    for (int c = 0; c < 8; ++c) acc[r][c] = 0.f;

  for (int k0 = 0; k0 < CDIM; k0 += 32) {
    // A tile: 64 rows x 32 cols, store transposed
    {
      const int row = t >> 3;          // 0..63
      const int c4 = (t & 7) * 4;      // 0..28
      float4 v = *reinterpret_cast<const float4*>(&A[(long)(row0 + row) * CDIM + k0 + c4]);
      AsT[c4 + 0][row] = v.x; AsT[c4 + 1][row] = v.y;
      AsT[c4 + 2][row] = v.z; AsT[c4 + 3][row] = v.w;
    }
    // B tile: 32 rows x 128 cols
    #pragma unroll
    for (int it = 0; it < 2; ++it) {
      const int f4 = t + 512 * it;     // 0..1023
      const int kk = f4 >> 5;
      const int cc = (f4 & 31) * 4;
      *reinterpret_cast<float4*>(&Bs[kk][cc]) =
          *reinterpret_cast<const float4*>(&wo[(long)(k0 + kk) * NOUT_ + cc]);
    }
    __syncthreads();
    #pragma unroll 4
    for (int kk = 0; kk < 32; ++kk) {
      const float2 a2 = *reinterpret_cast<const float2*>(&AsT[kk][2 * tr]);
      const float4 b0 = *reinterpret_cast<const float4*>(&Bs[kk][8 * tc]);
      const float4 b1v = *reinterpret_cast<const float4*>(&Bs[kk][8 * tc + 4]);
      const float av[2] = {a2.x, a2.y};
      const float bv[8] = {b0.x, b0.y, b0.z, b0.w, b1v.x, b1v.y, b1v.z, b1v.w};
      #pragma unroll
      for (int r = 0; r < 2; ++r)
        #pragma unroll
        for (int c = 0; c < 8; ++c) acc[r][c] += av[r] * bv[c];
    }
    __syncthreads();
  }

  // epilogue: +bwo, LN over 128 (16 threads per row), write
  #pragma unroll
  for (int rr = 0; rr < 2; ++rr) {
    float v[8];
    #pragma unroll
    for (int c = 0; c < 8; ++c) v[c] = acc[rr][c] + bwo[8 * tc + c];
    float s = 0.f;
    #pragma unroll
    for (int c = 0; c < 8; ++c) s += v[c];
    const float mu = rsum16(s) * (1.f / 128.f);
    float d2 = 0.f;
    #pragma unroll
    for (int c = 0; c < 8; ++c) { float d = v[c] - mu; d2 += d * d; }
    const float rstd = rsqrtf(rsum16(d2) * (1.f / 128.f) + LNEPS);
    float o[8];
    #pragma unroll
    for (int c = 0; c < 8; ++c)
      o[c] = (v[c] - mu) * rstd * gln[8 * tc + c] + bln[8 * tc + c];
    float* op = out + (long)(row0 + 2 * tr + rr) * NOUT_ + 8 * tc;
    *reinterpret_cast<float4*>(op) = make_float4(o[0], o[1], o[2], o[3]);
    *reinterpret_cast<float4*>(op + 4) = make_float4(o[4], o[5], o[6], o[7]);
  }
}

extern "C" void kernel_launch(void* const* d_in, const int* in_sizes, int n_in,
                              void* d_out, int out_size, void* d_ws, size_t ws_size,
                              hipStream_t stream) {
  const float* fp   = (const float*)d_in[0];
  const float* feat = (const float*)d_in[1];
  const float* ep   = (const float*)d_in[2];
  const float* w1   = (const float*)d_in[3];
  const float* b1   = (const float*)d_in[4];
  const float* g1   = (const float*)d_in[5];
  const float* be1  = (const float*)d_in[6];
  const float* w2   = (const float*)d_in[7];
  const float* b2   = (const float*)d_in[8];
  const float* wo   = (const float*)d_in[9];
  const float* bwo  = (const float*)d_in[10];
  const float* gln  = (const float*)d_in[11];
  const float* bln  = (const float*)d_in[12];
  float* out = (float*)d_out;
  float* A = (float*)d_ws;  // NTOT * CDIM floats = 64 MB

  k1_contract<<<NTOT, 256, 0, stream>>>(fp, feat, ep, w1, b1, g1, be1, w2, b2, A);
  k2_gemm_ln<<<NTOT / 64, 512, 0, stream>>>(A, wo, bwo, gln, bln, out);
}

// Round 2
// 323.500 us; speedup vs baseline: 1.2271x; 1.2271x over previous
//
#include <hip/hip_runtime.h>
#include <hip/hip_bf16.h>

#define KP    32
#define NIN_  64
#define RNK   16
#define NOUT_ 128
#define HID_  64
#define CDIM  1024   // RNK*NIN_
#define EPS_  1e-7f
#define LNEPS 1e-5f
#define NTOT  16384  // B*N

using short8 = __attribute__((ext_vector_type(8))) short;
using f32x4  = __attribute__((ext_vector_type(4))) float;

#define GLD16(gsrc, ldst) __builtin_amdgcn_global_load_lds( \
    (const __attribute__((address_space(1))) void*)(gsrc),  \
    (__attribute__((address_space(3))) void*)(ldst), 16, 0, 0)

__device__ __forceinline__ unsigned short f2bf(float x) {
  unsigned u = __float_as_uint(x);
  return (unsigned short)((u + 0x7fffu + ((u >> 16) & 1u)) >> 16);
}
__device__ __forceinline__ float rsum8(float v) {
  v += __shfl_xor(v, 1); v += __shfl_xor(v, 2); v += __shfl_xor(v, 4);
  return v;
}

// ---------------- prep: woT[n][k] = bf16(wo[k][n]) ----------------
__global__ __launch_bounds__(256) void k0_woT(const float* __restrict__ wo,
                                              unsigned short* __restrict__ woT) {
  __shared__ unsigned short S[64][129];
  const int t = threadIdx.x;
  const int k0 = blockIdx.x * 64;           // 16 blocks cover K=1024
  #pragma unroll
  for (int i = 0; i < 32; ++i) {            // load coalesced: 64k x 128n tile
    const int idx = i * 256 + t;
    const int k = idx >> 7, n = idx & 127;
    S[k][n] = f2bf(wo[(long)(k0 + k) * NOUT_ + n]);
  }
  __syncthreads();
  #pragma unroll
  for (int i = 0; i < 32; ++i) {            // store coalesced along k
    const int idx = i * 256 + t;
    const int n = idx >> 6, k = idx & 63;
    woT[(long)n * CDIM + k0 + k] = S[k][n];
  }
}

// ---------------- k1: per-point geometry + MLPs + contraction -> A (bf16) ----
__global__ __launch_bounds__(256) void k1_contract(
    const float* __restrict__ fp,   // (NTOT, KP, 3)
    const float* __restrict__ feat, // (NTOT, KP, NIN_)
    const float* __restrict__ ep,   // (NTOT, 3)
    const float* __restrict__ w1,   // (8, HID_)
    const float* __restrict__ b1, const float* __restrict__ g1,
    const float* __restrict__ be1,
    const float* __restrict__ w2,   // (HID_, RNK)
    const float* __restrict__ b2,
    unsigned short* __restrict__ A) // (NTOT, CDIM) bf16
{
  __shared__ __align__(16) float featS[KP * NIN_];   // 8 KB
  __shared__ __align__(16) float w1T[64][8];         // w1T[h][x] = w1[x][h]
  __shared__ __align__(16) float w2T[16][68];        // w2T[r][h] = w2[h][r]
  __shared__ __align__(16) float riS[KP][8];
  __shared__ __align__(16) float hdnS[KP][68];
  __shared__ __align__(16) float kern2[KP * RNK];    // [k][r]

  const int t = threadIdx.x;
  const long bn = blockIdx.x;

  // stage feat tile (direct-to-LDS, 16B/lane, linear dest)
  const float* fsrc = feat + bn * (KP * NIN_);
  GLD16(fsrc + t * 4, featS + t * 4);
  GLD16(fsrc + (t + 256) * 4, featS + (t + 256) * 4);

  // stage transposed small weights
  if (t < 64) {
    #pragma unroll
    for (int x = 0; x < 8; ++x) w1T[t][x] = w1[x * HID_ + t];
  }
  #pragma unroll
  for (int i = 0; i < 4; ++i) {
    const int idx = t + 256 * i;
    const int r = idx >> 6, hh = idx & 63;
    w2T[r][hh] = w2[hh * RNK + r];
  }

  // phase 1: rifeat (lanes 0..31, one per k)
  if (t < KP) {
    const float* prp = fp + (bn * KP + t) * 3;
    float prx = prp[0], pry = prp[1], prz = prp[2];
    const float* psp = ep + bn * 3;
    float psx = psp[0], psy = psp[1], psz = psp[2];

    float sx = prx, sy = pry, sz = prz;
    #pragma unroll
    for (int m = 16; m >= 1; m >>= 1) {
      sx += __shfl_xor(sx, m); sy += __shfl_xor(sy, m); sz += __shfl_xor(sz, m);
    }
    const float inv = 1.f / 32.f;
    float mx = sx * inv, my = sy * inv, mz = sz * inv;

    float l1x = mx - prx, l1y = my - pry, l1z = mz - prz;
    float l2x = prx - psx, l2y = pry - psy, l2z = prz - psz;
    float l3x = psx - mx, l3y = psy - my, l3z = psz - mz;
    float l1n = sqrtf(l1x * l1x + l1y * l1y + l1z * l1z);
    float l2n = sqrtf(l2x * l2x + l2y * l2y + l2z * l2z);
    float l3n = sqrtf(l3x * l3x + l3y * l3y + l3z * l3z);
    float th1 = (l1x * l2x + l1y * l2y + l1z * l2z) / (l1n * l2n + EPS_);
    float th2 = (l2x * l3x + l2y * l3y + l2z * l3z) / (l2n * l3n + EPS_);
    float th3 = (l3x * l1x + l3y * l1y + l3z * l1z) / (l3n * l1n + EPS_);
    float h   = sqrtf(prx * prx + pry * pry + prz * prz);
    float psn = sqrtf(psx * psx + psy * psy + psz * psz);
    // row 2 of Zm(-ps.z)@Ym(-pol)@Zm(-az) == ps/|ps|  =>  res2 = p̂s · p̂r
    float c = (psx * prx + psy * pry + psz * prz) / (psn * h);
    c = fminf(1.f, fmaxf(-1.f, c));
    float txj = acosf(c) * 0.31830988618379067f;

    riS[t][0] = txj; riS[t][1] = h;   riS[t][2] = l1n; riS[t][3] = l2n;
    riS[t][4] = l3n; riS[t][5] = th1; riS[t][6] = th2; riS[t][7] = th3;
  }
  __syncthreads();

  // phase 2: hdn = relu(LN(ri@w1 + b1)); thread -> (k = t>>3, s = t&7)
  {
    const int k = t >> 3, s = t & 7;
    const float4 rv0 = *reinterpret_cast<const float4*>(&riS[k][0]);
    const float4 rv1 = *reinterpret_cast<const float4*>(&riS[k][4]);
    float vals[8];
    #pragma unroll
    for (int j = 0; j < 8; ++j) {
      const int hh = s + 8 * j;
      const float4 wv0 = *reinterpret_cast<const float4*>(&w1T[hh][0]);
      const float4 wv1 = *reinterpret_cast<const float4*>(&w1T[hh][4]);
      vals[j] = b1[hh]
        + rv0.x * wv0.x + rv0.y * wv0.y + rv0.z * wv0.z + rv0.w * wv0.w
        + rv1.x * wv1.x + rv1.y * wv1.y + rv1.z * wv1.z + rv1.w * wv1.w;
    }
    float psum = 0.f;
    #pragma unroll
    for (int j = 0; j < 8; ++j) psum += vals[j];
    const float mu = rsum8(psum) * (1.f / 64.f);
    float vsum = 0.f;
    #pragma unroll
    for (int j = 0; j < 8; ++j) { float d = vals[j] - mu; vsum += d * d; }
    const float rstd = rsqrtf(rsum8(vsum) * (1.f / 64.f) + LNEPS);
    #pragma unroll
    for (int j = 0; j < 8; ++j) {
      const int hh = s + 8 * j;
      hdnS[k][hh] = fmaxf((vals[j] - mu) * rstd * g1[hh] + be1[hh], 0.f);
    }
  }
  __syncthreads();

  // phase 3: kern2[k][r] = b2[r] + hdn[k]·w2[:,r] via b128 dot products
  #pragma unroll
  for (int it = 0; it < 2; ++it) {
    const int idx = t + 256 * it;
    const int k = idx >> 4, r = idx & 15;
    float a = b2[r];
    #pragma unroll
    for (int h0 = 0; h0 < HID_; h0 += 4) {
      const float4 hv = *reinterpret_cast<const float4*>(&hdnS[k][h0]);
      const float4 wv = *reinterpret_cast<const float4*>(&w2T[r][h0]);
      a += hv.x * wv.x + hv.y * wv.y + hv.z * wv.z + hv.w * wv.w;
    }
    kern2[k * RNK + r] = a;
  }
  __syncthreads();

  // phase 4: cont[r][i] = sum_k kern2[k][r]*featS[k][i]; t<128, 2r x 4i each
  if (t < 128) {
    const int rp = t >> 4, iq = t & 15;
    float a00 = 0.f, a01 = 0.f, a02 = 0.f, a03 = 0.f;
    float a10 = 0.f, a11 = 0.f, a12 = 0.f, a13 = 0.f;
    #pragma unroll 8
    for (int k = 0; k < KP; ++k) {
      const float4 fv = *reinterpret_cast<const float4*>(&featS[k * NIN_ + iq * 4]);
      const float2 kv = *reinterpret_cast<const float2*>(&kern2[k * RNK + rp * 2]);
      a00 += kv.x * fv.x; a01 += kv.x * fv.y; a02 += kv.x * fv.z; a03 += kv.x * fv.w;
      a10 += kv.y * fv.x; a11 += kv.y * fv.y; a12 += kv.y * fv.z; a13 += kv.y * fv.w;
    }
    unsigned short* Ab = A + bn * CDIM;
    ushort4 o0 = make_ushort4(f2bf(a00), f2bf(a01), f2bf(a02), f2bf(a03));
    ushort4 o1 = make_ushort4(f2bf(a10), f2bf(a11), f2bf(a12), f2bf(a13));
    *reinterpret_cast<ushort4*>(&Ab[(rp * 2 + 0) * NIN_ + iq * 4]) = o0;
    *reinterpret_cast<ushort4*>(&Ab[(rp * 2 + 1) * NIN_ + iq * 4]) = o1;
  }
}

// ---------------- k2: bf16 MFMA GEMM (16384x1024 @ 1024x128) + bias + LN ----
__global__ __launch_bounds__(256) void k2_gemm_ln(
    const unsigned short* __restrict__ A,    // (NTOT, CDIM) bf16
    const unsigned short* __restrict__ woT,  // (NOUT_, CDIM) bf16
    const float* __restrict__ bwo, const float* __restrict__ gln,
    const float* __restrict__ bln, float* __restrict__ out)
{
  __shared__ __align__(16) unsigned short As[64 * 64];   // 8 KB (swizzled chunks)
  __shared__ __align__(16) unsigned short Bs[128 * 64];  // 16 KB (woT tile)
  __shared__ __align__(16) float Cs[64 * 132];           // 33 KB

  const int t = threadIdx.x;
  const int w = t >> 6, l = t & 63;
  const int mw = w & 1, nw = w >> 1;
  const long row0 = (long)blockIdx.x * 64;

  f32x4 acc[2][4];
  #pragma unroll
  for (int mt = 0; mt < 2; ++mt)
    #pragma unroll
    for (int nt = 0; nt < 4; ++nt) acc[mt][nt] = (f32x4){0.f, 0.f, 0.f, 0.f};

  for (int k0 = 0; k0 < CDIM; k0 += 64) {
    // stage As (64 rows x 64 k, bf16): linear LDS dest, pre-swizzled source col
    #pragma unroll
    for (int i = 0; i < 2; ++i) {
      const int idx = t + 256 * i;
      const int row = idx >> 3, c = idx & 7;
      const int cs = c ^ (row & 7);
      GLD16(A + (row0 + row) * CDIM + k0 + cs * 8, As + idx * 8);
    }
    // stage Bs (128 n-rows x 64 k)
    #pragma unroll
    for (int i = 0; i < 4; ++i) {
      const int idx = t + 256 * i;
      const int row = idx >> 3, c = idx & 7;
      const int cs = c ^ (row & 7);
      GLD16(woT + (long)row * CDIM + k0 + cs * 8, Bs + idx * 8);
    }
    __syncthreads();

    const int kg = l >> 4, m = l & 15;
    #pragma unroll
    for (int ks = 0; ks < 2; ++ks) {
      const int kc = ks * 4 + kg;
      short8 af[2], bfr[4];
      #pragma unroll
      for (int mt = 0; mt < 2; ++mt) {
        const int row = mw * 32 + mt * 16 + m;
        af[mt] = *reinterpret_cast<const short8*>(&As[row * 64 + ((kc ^ (row & 7)) << 3)]);
      }
      #pragma unroll
      for (int nt = 0; nt < 4; ++nt) {
        const int row = nw * 64 + nt * 16 + m;
        bfr[nt] = *reinterpret_cast<const short8*>(&Bs[row * 64 + ((kc ^ (row & 7)) << 3)]);
      }
      #pragma unroll
      for (int mt = 0; mt < 2; ++mt)
        #pragma unroll
        for (int nt = 0; nt < 4; ++nt)
          acc[mt][nt] = __builtin_amdgcn_mfma_f32_16x16x32_bf16(
              af[mt], bfr[nt], acc[mt][nt], 0, 0, 0);
    }
    __syncthreads();
  }

  // scatter accumulators to Cs (C/D layout: col=lane&15, row=(lane>>4)*4+r)
  #pragma unroll
  for (int mt = 0; mt < 2; ++mt)
    #pragma unroll
    for (int nt = 0; nt < 4; ++nt)
      #pragma unroll
      for (int r = 0; r < 4; ++r) {
        const int row = mw * 32 + mt * 16 + (l >> 4) * 4 + r;
        const int col = nw * 64 + nt * 16 + (l & 15);
        Cs[row * 132 + col] = acc[mt][nt][r];
      }
  __syncthreads();

  // LN over 128 cols: 4 threads per row
  {
    const int row = t >> 2, q = t & 3;
    float4 v[8];
    #pragma unroll
    for (int i = 0; i < 8; ++i) {
      float4 cv = *reinterpret_cast<const float4*>(&Cs[row * 132 + q * 32 + i * 4]);
      const float4 bv = *reinterpret_cast<const float4*>(&bwo[q * 32 + i * 4]);
      v[i] = make_float4(cv.x + bv.x, cv.y + bv.y, cv.z + bv.z, cv.w + bv.w);
    }
    float s = 0.f;
    #pragma unroll
    for (int i = 0; i < 8; ++i) s += v[i].x + v[i].y + v[i].z + v[i].w;
    s += __shfl_xor(s, 1); s += __shfl_xor(s, 2);
    const float mu = s * (1.f / 128.f);
    float d2 = 0.f;
    #pragma unroll
    for (int i = 0; i < 8; ++i) {
      float dx = v[i].x - mu, dy = v[i].y - mu, dz = v[i].z - mu, dw = v[i].w - mu;
      d2 += dx * dx + dy * dy + dz * dz + dw * dw;
    }
    d2 += __shfl_xor(d2, 1); d2 += __shfl_xor(d2, 2);
    const float rstd = rsqrtf(d2 * (1.f / 128.f) + LNEPS);
    float* op = out + (row0 + row) * NOUT_ + q * 32;
    #pragma unroll
    for (int i = 0; i < 8; ++i) {
      const float4 gv = *reinterpret_cast<const float4*>(&gln[q * 32 + i * 4]);
      const float4 bv = *reinterpret_cast<const float4*>(&bln[q * 32 + i * 4]);
      float4 o;
      o.x = (v[i].x - mu) * rstd * gv.x + bv.x;
      o.y = (v[i].y - mu) * rstd * gv.y + bv.y;
      o.z = (v[i].z - mu) * rstd * gv.z + bv.z;
      o.w = (v[i].w - mu) * rstd * gv.w + bv.w;
      *reinterpret_cast<float4*>(op + i * 4) = o;
    }
  }
}

extern "C" void kernel_launch(void* const* d_in, const int* in_sizes, int n_in,
                              void* d_out, int out_size, void* d_ws, size_t ws_size,
                              hipStream_t stream) {
  const float* fp   = (const float*)d_in[0];
  const float* feat = (const float*)d_in[1];
  const float* ep   = (const float*)d_in[2];
  const float* w1   = (const float*)d_in[3];
  const float* b1   = (const float*)d_in[4];
  const float* g1   = (const float*)d_in[5];
  const float* be1  = (const float*)d_in[6];
  const float* w2   = (const float*)d_in[7];
  const float* b2   = (const float*)d_in[8];
  const float* wo   = (const float*)d_in[9];
  const float* bwo  = (const float*)d_in[10];
  const float* gln  = (const float*)d_in[11];
  const float* bln  = (const float*)d_in[12];
  float* out = (float*)d_out;

  unsigned short* A   = (unsigned short*)d_ws;                          // 33.5 MB bf16
  unsigned short* woT = (unsigned short*)((char*)d_ws + (48u << 20));   // 256 KB bf16

  k0_woT<<<16, 256, 0, stream>>>(wo, woT);
  k1_contract<<<NTOT, 256, 0, stream>>>(fp, feat, ep, w1, b1, g1, be1, w2, b2, A);
  k2_gemm_ln<<<NTOT / 64, 256, 0, stream>>>(A, woT, bwo, gln, bln, out);
}

// Round 3
// 295.483 us; speedup vs baseline: 1.3435x; 1.0948x over previous
//
#include <hip/hip_runtime.h>
#include <hip/hip_bf16.h>

#define KP    32
#define NIN_  64
#define RNK   16
#define NOUT_ 128
#define HID_  64
#define CDIM  1024   // RNK*NIN_
#define EPS_  1e-7f
#define LNEPS 1e-5f
#define NTOT  16384  // B*N

using short8 = __attribute__((ext_vector_type(8))) short;
using f32x4  = __attribute__((ext_vector_type(4))) float;

#define GLD16(gsrc, ldst) __builtin_amdgcn_global_load_lds( \
    (const __attribute__((address_space(1))) void*)(gsrc),  \
    (__attribute__((address_space(3))) void*)(ldst), 16, 0, 0)

__device__ __forceinline__ unsigned short f2bf(float x) {
  unsigned u = __float_as_uint(x);
  return (unsigned short)((u + 0x7fffu + ((u >> 16) & 1u)) >> 16);
}

// ---------------- prep: woT[n][k] = bf16(wo[k][n]) ----------------
__global__ __launch_bounds__(256) void k0_woT(const float* __restrict__ wo,
                                              unsigned short* __restrict__ woT) {
  __shared__ unsigned short S[64][129];
  const int t = threadIdx.x;
  const int k0 = blockIdx.x * 64;
  #pragma unroll
  for (int i = 0; i < 32; ++i) {
    const int idx = i * 256 + t;
    const int k = idx >> 7, n = idx & 127;
    S[k][n] = f2bf(wo[(long)(k0 + k) * NOUT_ + n]);
  }
  __syncthreads();
  #pragma unroll
  for (int i = 0; i < 32; ++i) {
    const int idx = i * 256 + t;
    const int n = idx >> 6, k = idx & 63;
    woT[(long)n * CDIM + k0 + k] = S[k][n];
  }
}

// ---------------- k1: wave-synchronous per-point pipeline -> A (bf16) -------
// Block: 256 thr = 4 waves; each wave processes 4 points (grid 1024).
// Lane layout: lane = 2*k + hh (k=0..31 neighbor index, hh=0/1 owns 32 hidden).
__global__ __launch_bounds__(256) void k1_contract(
    const float* __restrict__ fp,   // (NTOT, KP, 3)
    const float* __restrict__ feat, // (NTOT, KP, NIN_)
    const float* __restrict__ ep,   // (NTOT, 3)
    const float* __restrict__ w1,   // (8, HID_)
    const float* __restrict__ b1, const float* __restrict__ g1,
    const float* __restrict__ be1,
    const float* __restrict__ w2,   // (HID_, RNK)
    const float* __restrict__ b2,
    unsigned short* __restrict__ A) // (NTOT, CDIM) bf16
{
  __shared__ float w1T[64][8];           // w1T[h][x] = w1[x][h]
  __shared__ float w2S[64][16];          // natural layout (broadcast reads)
  __shared__ float b1S[64], g1S[64], beS[64], b2S[16];
  __shared__ __align__(16) float featW[4][KP * NIN_];  // 8 KB per wave
  __shared__ float kernS[4][KP][17];     // pad 17: gcd(17,32)=1 -> conflict-free

  const int t = threadIdx.x;
  const int wv = t >> 6, lane = t & 63;
  const int hh = lane & 1, kk = lane >> 1;

  // one-time weight staging
  if (t < 64) {
    #pragma unroll
    for (int x = 0; x < 8; ++x) w1T[t][x] = w1[x * HID_ + t];
    b1S[t] = b1[t]; g1S[t] = g1[t]; beS[t] = be1[t];
  }
  reinterpret_cast<float4*>(&w2S[0][0])[t] = reinterpret_cast<const float4*>(w2)[t];
  if (t < 16) b2S[t] = b2[t];
  __syncthreads();

  #pragma unroll 1
  for (int pi = 0; pi < 4; ++pi) {
    const long pt = (long)blockIdx.x * 16 + wv * 4 + pi;

    __builtin_amdgcn_sched_barrier(0);
    // issue per-wave feat staging early; drained before phase D
    {
      const float* fsrc = feat + pt * (KP * NIN_);
      float* fdst = &featW[wv][0];
      #pragma unroll
      for (int j = 0; j < 8; ++j)
        GLD16(fsrc + j * 256 + lane * 4, fdst + j * 256 + lane * 4);
    }

    // ---- phase A: geometry for neighbor kk ----
    const float* prp = fp + (pt * KP + kk) * 3;
    float prx = prp[0], pry = prp[1], prz = prp[2];
    const float* psp = ep + pt * 3;
    float psx = psp[0], psy = psp[1], psz = psp[2];

    float sx = prx, sy = pry, sz = prz;
    #pragma unroll
    for (int m = 2; m <= 32; m <<= 1) {
      sx += __shfl_xor(sx, m); sy += __shfl_xor(sy, m); sz += __shfl_xor(sz, m);
    }
    const float inv = 1.f / 32.f;
    const float mx = sx * inv, my = sy * inv, mz = sz * inv;

    const float l1x = mx - prx, l1y = my - pry, l1z = mz - prz;
    const float l2x = prx - psx, l2y = pry - psy, l2z = prz - psz;
    const float l3x = psx - mx, l3y = psy - my, l3z = psz - mz;
    const float l1n = sqrtf(l1x * l1x + l1y * l1y + l1z * l1z);
    const float l2n = sqrtf(l2x * l2x + l2y * l2y + l2z * l2z);
    const float l3n = sqrtf(l3x * l3x + l3y * l3y + l3z * l3z);
    const float th1 = (l1x * l2x + l1y * l2y + l1z * l2z) / (l1n * l2n + EPS_);
    const float th2 = (l2x * l3x + l2y * l3y + l2z * l3z) / (l2n * l3n + EPS_);
    const float th3 = (l3x * l1x + l3y * l1y + l3z * l1z) / (l3n * l1n + EPS_);
    const float hn  = sqrtf(prx * prx + pry * pry + prz * prz);
    const float psn = sqrtf(psx * psx + psy * psy + psz * psz);
    float c = (psx * prx + psy * pry + psz * prz) / (psn * hn);
    c = fminf(1.f, fmaxf(-1.f, c));
    const float ri0 = acosf(c) * 0.31830988618379067f;
    const float ri1 = hn,  ri2 = l1n, ri3 = l2n;
    const float ri4 = l3n, ri5 = th1, ri6 = th2, ri7 = th3;

    // ---- phase B: vals[j] = (ri @ w1 + b1)[h], h = hh*32+j; LN lane-pair ----
    float vals[32];
    #pragma unroll
    for (int j = 0; j < 32; ++j) {
      const int h = hh * 32 + j;
      const float4 wa = *reinterpret_cast<const float4*>(&w1T[h][0]);
      const float4 wb = *reinterpret_cast<const float4*>(&w1T[h][4]);
      vals[j] = b1S[h]
        + ri0 * wa.x + ri1 * wa.y + ri2 * wa.z + ri3 * wa.w
        + ri4 * wb.x + ri5 * wb.y + ri6 * wb.z + ri7 * wb.w;
    }
    float s = 0.f;
    #pragma unroll
    for (int j = 0; j < 32; ++j) s += vals[j];
    s += __shfl_xor(s, 1);
    const float mu = s * (1.f / 64.f);
    float v2 = 0.f;
    #pragma unroll
    for (int j = 0; j < 32; ++j) { const float d = vals[j] - mu; v2 += d * d; }
    v2 += __shfl_xor(v2, 1);
    const float rstd = rsqrtf(v2 * (1.f / 64.f) + LNEPS);
    #pragma unroll
    for (int j = 0; j < 32; ++j) {
      const int h = hh * 32 + j;
      vals[j] = fmaxf((vals[j] - mu) * rstd * g1S[h] + beS[h], 0.f);
    }

    // ---- phase C: kern[r] = b2[r] + sum_h hdn[h]*w2[h][r] ----
    float kern[16];
    #pragma unroll
    for (int r = 0; r < 16; ++r) kern[r] = 0.f;
    #pragma unroll
    for (int j = 0; j < 32; ++j) {
      const int h = hh * 32 + j;
      const float hv = vals[j];
      #pragma unroll
      for (int rc = 0; rc < 4; ++rc) {
        const float4 wr = *reinterpret_cast<const float4*>(&w2S[h][rc * 4]);
        kern[rc * 4 + 0] += hv * wr.x;
        kern[rc * 4 + 1] += hv * wr.y;
        kern[rc * 4 + 2] += hv * wr.z;
        kern[rc * 4 + 3] += hv * wr.w;
      }
    }
    #pragma unroll
    for (int r = 0; r < 16; ++r) kern[r] += __shfl_xor(kern[r], 1);
    #pragma unroll
    for (int q = 0; q < 8; ++q)
      kernS[wv][kk][hh * 8 + q] = kern[hh * 8 + q] + b2S[hh * 8 + q];

    // ---- phase D: cont[r][i] = sum_k kern[k][r]*feat[k][i] ----
    asm volatile("s_waitcnt vmcnt(0)" ::: "memory");
    __builtin_amdgcn_sched_barrier(0);
    const int rr = lane & 15, riq = lane >> 4;
    f32x4 a0 = {0.f,0.f,0.f,0.f}, a1 = a0, a2 = a0, a3 = a0;
    #pragma unroll 8
    for (int kq = 0; kq < 32; ++kq) {
      const float kv = kernS[wv][kq][rr];
      const float* fb = &featW[wv][kq * 64 + riq * 4];
      const f32x4 f0 = *reinterpret_cast<const f32x4*>(fb);
      const f32x4 f1 = *reinterpret_cast<const f32x4*>(fb + 16);
      const f32x4 f2 = *reinterpret_cast<const f32x4*>(fb + 32);
      const f32x4 f3 = *reinterpret_cast<const f32x4*>(fb + 48);
      a0 += kv * f0; a1 += kv * f1; a2 += kv * f2; a3 += kv * f3;
    }
    unsigned short* Ap = A + pt * CDIM + rr * 64 + riq * 4;
    *reinterpret_cast<ushort4*>(Ap +  0) = make_ushort4(f2bf(a0[0]), f2bf(a0[1]), f2bf(a0[2]), f2bf(a0[3]));
    *reinterpret_cast<ushort4*>(Ap + 16) = make_ushort4(f2bf(a1[0]), f2bf(a1[1]), f2bf(a1[2]), f2bf(a1[3]));
    *reinterpret_cast<ushort4*>(Ap + 32) = make_ushort4(f2bf(a2[0]), f2bf(a2[1]), f2bf(a2[2]), f2bf(a2[3]));
    *reinterpret_cast<ushort4*>(Ap + 48) = make_ushort4(f2bf(a3[0]), f2bf(a3[1]), f2bf(a3[2]), f2bf(a3[3]));
  }
}

// ---------------- k2: bf16 MFMA GEMM + bias + LN, 2-phase pipelined ---------
__global__ __launch_bounds__(256) void k2_gemm_ln(
    const unsigned short* __restrict__ A,    // (NTOT, CDIM) bf16
    const unsigned short* __restrict__ woT,  // (NOUT_, CDIM) bf16
    const float* __restrict__ bwo, const float* __restrict__ gln,
    const float* __restrict__ bln, float* __restrict__ out)
{
  __shared__ __align__(16) char smem[49152];
  unsigned short* AsB = reinterpret_cast<unsigned short*>(smem);           // [2][4096]
  unsigned short* BsB = reinterpret_cast<unsigned short*>(smem + 16384);   // [2][8192]
  float* Cs = reinterpret_cast<float*>(smem);  // epilogue overlay [64*132]

  const int t = threadIdx.x;
  const int w = t >> 6, l = t & 63;
  const int mw = w & 1, nw = w >> 1;
  const long row0 = (long)blockIdx.x * 64;

  f32x4 acc[2][4];
  #pragma unroll
  for (int mt = 0; mt < 2; ++mt)
    #pragma unroll
    for (int nt = 0; nt < 4; ++nt) acc[mt][nt] = (f32x4){0.f, 0.f, 0.f, 0.f};

  auto stage = [&](int buf, int k0) {
    unsigned short* Ad = AsB + buf * 4096;
    unsigned short* Bd = BsB + buf * 8192;
    #pragma unroll
    for (int i = 0; i < 2; ++i) {
      const int idx = t + 256 * i;
      const int row = idx >> 3, c = idx & 7;
      const int cs = c ^ (row & 7);
      GLD16(A + (row0 + row) * CDIM + k0 + cs * 8, Ad + idx * 8);
    }
    #pragma unroll
    for (int i = 0; i < 4; ++i) {
      const int idx = t + 256 * i;
      const int row = idx >> 3, c = idx & 7;
      const int cs = c ^ (row & 7);
      GLD16(woT + (long)row * CDIM + k0 + cs * 8, Bd + idx * 8);
    }
  };

  stage(0, 0);
  asm volatile("s_waitcnt vmcnt(0)" ::: "memory");
  __builtin_amdgcn_s_barrier();

  for (int c = 0; c < 16; ++c) {
    const int cur = c & 1;
    if (c < 15) stage(cur ^ 1, (c + 1) * 64);  // prefetch next chunk

    const unsigned short* Ab = AsB + cur * 4096;
    const unsigned short* Bb = BsB + cur * 8192;
    const int kg = l >> 4, m = l & 15;
    #pragma unroll
    for (int ks = 0; ks < 2; ++ks) {
      const int kc = ks * 4 + kg;
      short8 af[2], bfr[4];
      #pragma unroll
      for (int mt = 0; mt < 2; ++mt) {
        const int row = mw * 32 + mt * 16 + m;
        af[mt] = *reinterpret_cast<const short8*>(&Ab[row * 64 + ((kc ^ (row & 7)) << 3)]);
      }
      #pragma unroll
      for (int nt = 0; nt < 4; ++nt) {
        const int row = nw * 64 + nt * 16 + m;
        bfr[nt] = *reinterpret_cast<const short8*>(&Bb[row * 64 + ((kc ^ (row & 7)) << 3)]);
      }
      #pragma unroll
      for (int mt = 0; mt < 2; ++mt)
        #pragma unroll
        for (int nt = 0; nt < 4; ++nt)
          acc[mt][nt] = __builtin_amdgcn_mfma_f32_16x16x32_bf16(
              af[mt], bfr[nt], acc[mt][nt], 0, 0, 0);
    }
    asm volatile("s_waitcnt vmcnt(0)" ::: "memory");
    __builtin_amdgcn_s_barrier();
  }

  // epilogue: scatter acc -> Cs (overlays staging; safe after final barrier)
  #pragma unroll
  for (int mt = 0; mt < 2; ++mt)
    #pragma unroll
    for (int nt = 0; nt < 4; ++nt)
      #pragma unroll
      for (int r = 0; r < 4; ++r) {
        const int row = mw * 32 + mt * 16 + (l >> 4) * 4 + r;
        const int col = nw * 64 + nt * 16 + (l & 15);
        Cs[row * 132 + col] = acc[mt][nt][r];
      }
  __syncthreads();

  // LN over 128 cols: 4 threads per row
  {
    const int row = t >> 2, q = t & 3;
    float4 v[8];
    #pragma unroll
    for (int i = 0; i < 8; ++i) {
      const float4 cv = *reinterpret_cast<const float4*>(&Cs[row * 132 + q * 32 + i * 4]);
      const float4 bv = *reinterpret_cast<const float4*>(&bwo[q * 32 + i * 4]);
      v[i] = make_float4(cv.x + bv.x, cv.y + bv.y, cv.z + bv.z, cv.w + bv.w);
    }
    float s = 0.f;
    #pragma unroll
    for (int i = 0; i < 8; ++i) s += v[i].x + v[i].y + v[i].z + v[i].w;
    s += __shfl_xor(s, 1); s += __shfl_xor(s, 2);
    const float mu = s * (1.f / 128.f);
    float d2 = 0.f;
    #pragma unroll
    for (int i = 0; i < 8; ++i) {
      const float dx = v[i].x - mu, dy = v[i].y - mu, dz = v[i].z - mu, dw = v[i].w - mu;
      d2 += dx * dx + dy * dy + dz * dz + dw * dw;
    }
    d2 += __shfl_xor(d2, 1); d2 += __shfl_xor(d2, 2);
    const float rstd = rsqrtf(d2 * (1.f / 128.f) + LNEPS);
    float* op = out + (row0 + row) * NOUT_ + q * 32;
    #pragma unroll
    for (int i = 0; i < 8; ++i) {
      const float4 gv = *reinterpret_cast<const float4*>(&gln[q * 32 + i * 4]);
      const float4 bv = *reinterpret_cast<const float4*>(&bln[q * 32 + i * 4]);
      float4 o;
      o.x = (v[i].x - mu) * rstd * gv.x + bv.x;
      o.y = (v[i].y - mu) * rstd * gv.y + bv.y;
      o.z = (v[i].z - mu) * rstd * gv.z + bv.z;
      o.w = (v[i].w - mu) * rstd * gv.w + bv.w;
      *reinterpret_cast<float4*>(op + i * 4) = o;
    }
  }
}

extern "C" void kernel_launch(void* const* d_in, const int* in_sizes, int n_in,
                              void* d_out, int out_size, void* d_ws, size_t ws_size,
                              hipStream_t stream) {
  const float* fp   = (const float*)d_in[0];
  const float* feat = (const float*)d_in[1];
  const float* ep   = (const float*)d_in[2];
  const float* w1   = (const float*)d_in[3];
  const float* b1   = (const float*)d_in[4];
  const float* g1   = (const float*)d_in[5];
  const float* be1  = (const float*)d_in[6];
  const float* w2   = (const float*)d_in[7];
  const float* b2   = (const float*)d_in[8];
  const float* wo   = (const float*)d_in[9];
  const float* bwo  = (const float*)d_in[10];
  const float* gln  = (const float*)d_in[11];
  const float* bln  = (const float*)d_in[12];
  float* out = (float*)d_out;

  unsigned short* A   = (unsigned short*)d_ws;                          // 33.5 MB bf16
  unsigned short* woT = (unsigned short*)((char*)d_ws + (48u << 20));   // 256 KB bf16

  k0_woT<<<16, 256, 0, stream>>>(wo, woT);
  k1_contract<<<1024, 256, 0, stream>>>(fp, feat, ep, w1, b1, g1, be1, w2, b2, A);
  k2_gemm_ln<<<NTOT / 64, 256, 0, stream>>>(A, woT, bwo, gln, bln, out);
}